// Round 6
// baseline (1764.218 us; speedup 1.0000x reference)
//
#include <hip/hip_runtime.h>
#include <math.h>

// Codebook argmin via fp16 MFMA: B=16, K=512, C=512, H=W=64.
// R3: K-SPLIT (256 clusters/block) -> 3 waves/SIMD, 237->141us.
// R4: parallel merge + recheck kernels (combine was serializing at 153us).
// R5: 4 blocks/CU via LDS=40960; flat -> kernel is pipe-demand-sum bound.
// R6: SINGLE fp16 MFMA (v_mfma_f32_32x32x16_f16) replaces the 3-MFMA
// split-bf16. fp16 cross error sigma ~0.009; MARGIN raised 0.02 -> 0.15
// (~11 sigma) and the fp64 recheck absorbs the extra near-tie pixels.
// Chunk cost drops: MFMA 12->4, ds_read 8->4, converts halve, wcc 1MB->512KB,
// LDS 40960->20480 (8 blocks/CU). Counted-vmcnt 2-phase pipeline kept
// (stage=2 loads/wave: steady waits vmcnt(6)/vmcnt(4)).

#define NK   512
#define NC   512
#define NHW  4096
#define NPX  65536            // 16 * 4096 pixels
#define MARGIN 0.15f

typedef unsigned short u16;
typedef __attribute__((ext_vector_type(8)))  _Float16 half8;
typedef __attribute__((ext_vector_type(8)))  unsigned short ushort8;
typedef __attribute__((ext_vector_type(16))) float  f32x16;

__device__ __forceinline__ u16 f2h(float f) {
    return __builtin_bit_cast(u16, (_Float16)f);   // v_cvt_f16_f32, RN
}

// Pack cluster centers into fp16 MFMA A-operand fragment order, grouped by
// k-half, and compute 0.5*c_sq (exact fp32). Also zeroes the flag counter.
// wcc layout: [chunk 32][half 2][unit 8][lane 64][8 fp16];
// unit = local m-tile (32 clusters each).
__global__ __launch_bounds__(64) void prep_pack(const float* __restrict__ cc,
                                                u16* __restrict__ wcc,
                                                float* __restrict__ shalf,
                                                int* __restrict__ gcnt) {
    const int k    = blockIdx.x;
    const int lane = threadIdx.x;      // 64 j-groups of 8 channels
    if (k == 0 && lane == 0) gcnt[0] = 0;
    const int c0   = lane * 8;
    const float* row = cc + (size_t)k * NC + c0;
    ushort8 hi;
    float sum = 0.f;
    #pragma unroll
    for (int i = 0; i < 8; ++i) {
        float v = row[i];
        sum = fmaf(v, v, sum);
        hi[i] = f2h(v);
    }
    const int ch  = c0 >> 4;           // 16-channel chunk
    const int kh  = (c0 >> 3) & 1;     // which 8-chan octet of the chunk
    const int mtg = k >> 5;            // global m-tile 0..15
    const int h   = mtg >> 3;          // k-half
    const int mtl = mtg & 7;           // local m-tile 0..7
    const int ls  = (k & 31) + 32 * kh;
    *(ushort8*)(wcc + (((size_t)(ch * 2 + h) * 8 + mtl) * 64 + ls) * 8) = hi;
    #pragma unroll
    for (int off = 32; off > 0; off >>= 1) sum += __shfl_down(sum, off, 64);
    if (lane == 0) shalf[k] = 0.5f * sum;
}

__global__ __launch_bounds__(256, 8) void codebook_mfma(
        const float* __restrict__ x,
        const u16* __restrict__ wcc,
        const float* __restrict__ shalf,
        float* __restrict__ cbv,          // [2][NPX] best v per half
        float* __restrict__ csv,          // [2][NPX] second v per half
        int*   __restrict__ ckk)          // [2][NPX] best k (global) per half
{
    __shared__ __align__(16) u16 cs0[8 * 512];    // 8KB cluster frags, buf 0
    __shared__ __align__(16) u16 cs1[8 * 512];    // 8KB cluster frags, buf 1
    __shared__ __align__(16) u16 xs0[2 * 512];    // 2KB x frags, buf 0
    __shared__ __align__(16) u16 xs1[2 * 512];    // 2KB x frags, buf 1
    // total 20480B -> 8 blocks/CU. c_sq lives in the epilogue overlay.

    const int tid  = threadIdx.x;
    const int w    = tid >> 6;
    const int lane = tid & 63;

    const int h   = blockIdx.x & 1;               // k-half
    const int gp0 = (blockIdx.x >> 1) * 64;       // pixel-group base
    const float* xb = x + (size_t)(gp0 >> 12) * (NC * NHW) + (gp0 & (NHW - 1));

    f32x16 acc[2][2] = {};

    // x staging assignment: pixel p, chunk-octet kh, j-quarter jq (4 channels)
    const int p   = tid & 63;
    const int xkh = w & 1;
    const int jq  = w >> 1;
    const int xoff = ((p >> 5) * 64 + ((p & 31) + 32 * xkh)) * 8 + jq * 4;
    const float* xp = xb + (size_t)(xkh * 8 + jq * 4) * NHW + p;

    float fxa[4], fxb[4];                        // 2-deep x prefetch registers

    auto xload = [&](float* fx, int ch) {
        const float* xc = xp + (size_t)ch * 16 * NHW;
        fx[0] = xc[0];
        fx[1] = xc[NHW];
        fx[2] = xc[2 * NHW];
        fx[3] = xc[3 * NHW];
    };
    auto xwrite = [&](const float* fx, u16* xs) {
        u16 h0 = f2h(fx[0]), h1 = f2h(fx[1]), h2 = f2h(fx[2]), h3 = f2h(fx[3]);
        uint2 hv = make_uint2((unsigned)h0 | ((unsigned)h1 << 16),
                              (unsigned)h2 | ((unsigned)h3 << 16));
        *(uint2*)&xs[xoff] = hv;
    };
    // 8 units x 1KB = 8KB per chunk; 2 gload_lds per wave.
    auto stage_cs = [&](int ch, u16* dst) {
        #pragma unroll
        for (int i = 0; i < 2; ++i) {
            const int u = w * 2 + i;
            const u16* g = wcc + (((size_t)(ch * 2 + h) * 8 + u) * 64 + lane) * 8;
            __builtin_amdgcn_global_load_lds(
                (const __attribute__((address_space(1))) void*)g,
                (__attribute__((address_space(3))) void*)(dst + u * 512),
                16, 0, 0);
        }
    };
    auto compute = [&](const u16* csb, const u16* xsb) {
        __builtin_amdgcn_s_setprio(1);
        half8 bh[2];
        #pragma unroll
        for (int nt = 0; nt < 2; ++nt)
            bh[nt] = *(const half8*)&xsb[((size_t)nt * 64 + lane) * 8];
        #pragma unroll
        for (int mtl2 = 0; mtl2 < 2; ++mtl2) {
            const int gm = w * 2 + mtl2;          // local m-tile 0..7
            half8 ah = *(const half8*)&csb[((size_t)gm * 64 + lane) * 8];
            #pragma unroll
            for (int nt = 0; nt < 2; ++nt)
                acc[mtl2][nt] = __builtin_amdgcn_mfma_f32_32x32x16_f16(ah, bh[nt], acc[mtl2][nt], 0, 0, 0);
        }
        __builtin_amdgcn_s_setprio(0);
    };

    // vmcnt accounting (issue order pinned by sched_barrier(0)):
    // steady entry: fx_cur 4 outstanding. +2 stage -> 6; +4 xload -> 10.
    // vmcnt(6): fx_cur drained. vmcnt(4): stage drained, fx_nxt stays in
    // flight ACROSS the barrier.
    auto phase = [&](int t, u16* cs_cur, u16* cs_nxt, u16* xs_cur, u16* xs_nxt,
                     float* fx_cur, float* fx_nxt) {
        stage_cs(t + 1, cs_nxt);
        __builtin_amdgcn_sched_barrier(0);
        xload(fx_nxt, t + 2);
        asm volatile("s_waitcnt vmcnt(6)" ::: "memory");
        xwrite(fx_cur, xs_nxt);
        compute(cs_cur, xs_cur);
        asm volatile("s_waitcnt vmcnt(4) lgkmcnt(0)" ::: "memory");
        __builtin_amdgcn_s_barrier();
        __builtin_amdgcn_sched_barrier(0);
    };

    // ---- prologue ----
    xload(fxa, 0);                                    // 4 (oldest)
    __builtin_amdgcn_sched_barrier(0);
    stage_cs(0, cs0);                                 // +2 -> 6
    __builtin_amdgcn_sched_barrier(0);
    xload(fxb, 1);                                    // +4 -> 10
    asm volatile("s_waitcnt vmcnt(6)" ::: "memory");  // fxa ready
    xwrite(fxa, xs0);
    asm volatile("s_waitcnt vmcnt(4) lgkmcnt(0)" ::: "memory"); // cs0 done
    __builtin_amdgcn_s_barrier();
    __builtin_amdgcn_sched_barrier(0);

    // ---- main loop: chunks 0..29 ----
    for (int t = 0; t < 30; t += 2) {
        phase(t,     cs0, cs1, xs0, xs1, fxb, fxa);
        phase(t + 1, cs1, cs0, xs1, xs0, fxa, fxb);
    }

    // ---- tail: chunk 30 computes, chunk 31 staged ----
    stage_cs(31, cs1);                                // fxb(4) + 2 -> 6
    asm volatile("s_waitcnt vmcnt(2)" ::: "memory");  // fxb ready
    xwrite(fxb, xs1);
    compute(cs0, xs0);
    asm volatile("s_waitcnt vmcnt(0) lgkmcnt(0)" ::: "memory");
    __builtin_amdgcn_s_barrier();
    __builtin_amdgcn_sched_barrier(0);
    compute(cs1, xs1);
    __syncthreads();

    // ---- epilogue: per-half top-2 -> ws (overlays cs0, 7KB <= 8KB) ----
    float* cand_v = (float*)cs0;             // 2KB
    float* cand_s = cand_v + 512;            // 2KB
    int*   cand_k = (int*)(cand_s + 512);    // 2KB
    float* sh_ep  = (float*)(cand_k + 512);  // 1KB: 0.5*c_sq for this half

    sh_ep[tid] = shalf[h * 256 + tid];
    __syncthreads();

    const int qb = lane >> 5;
    #pragma unroll
    for (int nt = 0; nt < 2; ++nt) {
        float best = -INFINITY, sec = -INFINITY;
        int bk = 0;
        #pragma unroll
        for (int mtl2 = 0; mtl2 < 2; ++mtl2) {
            const int kbase = w * 64 + mtl2 * 32 + 4 * qb;
            #pragma unroll
            for (int reg = 0; reg < 16; ++reg) {
                const int k = kbase + (reg & 3) + 8 * (reg >> 2);  // ascending
                const float v = acc[mtl2][nt][reg] - sh_ep[k];
                if (v > best) { sec = best; best = v; bk = k; }
                else if (v > sec) sec = v;
            }
        }
        const int pc   = nt * 32 + (lane & 31);
        const int slot = w * 2 + qb;
        cand_v[pc * 8 + slot] = best;
        cand_s[pc * 8 + slot] = sec;
        cand_k[pc * 8 + slot] = bk;
    }
    __syncthreads();

    if (tid < 64) {
        float best = -INFINITY, sec = -INFINITY;
        int bk = 1 << 30;
        #pragma unroll
        for (int s = 0; s < 8; ++s) {
            float v  = cand_v[tid * 8 + s];
            float v2 = cand_s[tid * 8 + s];
            int  kk  = cand_k[tid * 8 + s];
            if (v > best || (v == best && kk < bk)) {
                sec = fmaxf(sec, best);
                best = v; bk = kk;
            } else sec = fmaxf(sec, v);
            sec = fmaxf(sec, v2);
        }
        const int gpx = gp0 + tid;
        cbv[h * NPX + gpx] = best;
        csv[h * NPX + gpx] = sec;
        ckk[h * NPX + gpx] = h * 256 + bk;
    }
}

// Per-pixel merge of the two k-halves; writes out; compacts near-tie pixels
// into a global list for the recheck kernel.
__global__ __launch_bounds__(256) void merge(
        const float* __restrict__ cbv,
        const float* __restrict__ csv,
        const int*   __restrict__ ckk,
        int* __restrict__ out,
        int* __restrict__ glist,
        int* __restrict__ gcnt)
{
    const int px = blockIdx.x * 256 + threadIdx.x;

    const float b0 = cbv[px],        b1 = cbv[NPX + px];
    const float s0 = csv[px],        s1 = csv[NPX + px];
    const int   k0 = ckk[px],        k1 = ckk[NPX + px];

    float best, sec; int bk;
    if (b0 >= b1) { best = b0; bk = k0; sec = fmaxf(s0, b1); }
    else          { best = b1; bk = k1; sec = fmaxf(s1, b0); }

    out[px] = bk;
    if (best - sec < MARGIN) {
        int i = atomicAdd(gcnt, 1);
        glist[i] = px;
    }
}

// One BLOCK per flagged pixel (grid-stride over the compacted list):
// cooperative fp64 exact distance over all 512 clusters.
__global__ __launch_bounds__(256) void recheck(
        const float* __restrict__ x,
        const float* __restrict__ cc,
        const int*   __restrict__ glist,
        const int*   __restrict__ gcnt,
        int* __restrict__ out)
{
    __shared__ float  xcol[NC];
    __shared__ double dvv[256];
    __shared__ int    dii[256];

    const int tid = threadIdx.x;
    const int n   = gcnt[0];

    for (int idx = blockIdx.x; idx < n; idx += gridDim.x) {
        const int gpx = glist[idx];
        const float* xb = x + (size_t)(gpx >> 12) * (NC * NHW);
        const int hw = gpx & (NHW - 1);
        for (int c = tid; c < NC; c += 256)
            xcol[c] = xb[(size_t)c * NHW + hw];
        __syncthreads();
        double bd = 1e300;
        int bkk = 1 << 30;
        #pragma unroll
        for (int r = 0; r < 2; ++r) {
            const int k = tid + r * 256;
            const float4* crow = (const float4*)(cc + (size_t)k * NC);
            const float4* xc4  = (const float4*)xcol;
            double da = 0.0, db = 0.0;           // 2-way split: halve chain latency
            for (int c4 = 0; c4 < NC / 4; ++c4) {
                float4 cv = crow[c4], xv = xc4[c4];
                double d0 = (double)xv.x - (double)cv.x;
                double d1 = (double)xv.y - (double)cv.y;
                double d2 = (double)xv.z - (double)cv.z;
                double d3 = (double)xv.w - (double)cv.w;
                da = fma(d0, d0, da); db = fma(d1, d1, db);
                da = fma(d2, d2, da); db = fma(d3, d3, db);
            }
            double d = da + db;
            if (d < bd || (d == bd && k < bkk)) { bd = d; bkk = k; }
        }
        dvv[tid] = bd; dii[tid] = bkk;
        __syncthreads();
        for (int srd = 128; srd > 0; srd >>= 1) {
            if (tid < srd) {
                double ov = dvv[tid + srd]; int oi = dii[tid + srd];
                if (ov < dvv[tid] || (ov == dvv[tid] && oi < dii[tid])) {
                    dvv[tid] = ov; dii[tid] = oi;
                }
            }
            __syncthreads();
        }
        if (tid == 0) out[gpx] = dii[0];
        __syncthreads();
    }
}

extern "C" void kernel_launch(void* const* d_in, const int* in_sizes, int n_in,
                              void* d_out, int out_size, void* d_ws, size_t ws_size,
                              hipStream_t stream) {
    const float* x  = (const float*)d_in[0];   // (16, 512, 64, 64) f32
    const float* cc = (const float*)d_in[1];   // (1, 512, 512, 1, 1) f32 -> [k][c]
    int* out = (int*)d_out;                    // (16, 1, 64, 64) int32

    float* shalf = (float*)d_ws;                          // 512 floats (2KB)
    u16*   wcc   = (u16*)(shalf + NK);                    // 512KB frag-ordered fp16
    float* cbv   = (float*)(wcc + 32 * 2 * 8 * 64 * 8);   // 2*NPX floats
    float* csv   = cbv + 2 * NPX;                         // 2*NPX floats
    int*   ckk   = (int*)(csv + 2 * NPX);                 // 2*NPX ints
    int*   glist = ckk + 2 * NPX;                         // NPX ints
    int*   gcnt  = glist + NPX;                           // 1 int

    prep_pack<<<NK, 64, 0, stream>>>(cc, wcc, shalf, gcnt);
    codebook_mfma<<<(NPX / 64) * 2, 256, 0, stream>>>(x, wcc, shalf, cbv, csv, ckk);
    merge<<<NPX / 256, 256, 0, stream>>>(cbv, csv, ckk, out, glist, gcnt);
    recheck<<<512, 256, 0, stream>>>(x, cc, glist, gcnt, out);
}

// Round 7
// 393.617 us; speedup vs baseline: 4.4821x; 4.4821x over previous
//
#include <hip/hip_runtime.h>
#include <math.h>

// Codebook argmin via fp16 MFMA: B=16, K=512, C=512, H=W=64.
// R3: K-SPLIT (256 clusters/block) -> 3 waves/SIMD, 237->141us.
// R4: parallel merge + recheck kernels (combine was serializing at 153us).
// R5: 4 blocks/CU via LDS=40960; flat -> kernel is pipe-demand-sum bound.
// R6: single fp16 MFMA (4 MFMA/chunk instead of 12), MARGIN 0.02->0.15 with
// fp64 recheck absorbing fp16 error (sigma ~0.009, margin ~11 sigma).
// R6 BUG: __launch_bounds__(256,8) capped regs at 64/wave < 64-AGPR
// accumulator -> full scratch spill (WRITE_SIZE 3.8GB, 1466us).
// R7: __launch_bounds__(256,4) (cap 128 = 64 acc + <=64 arch, proven to
// close in R5). Everything else from R6 kept.

#define NK   512
#define NC   512
#define NHW  4096
#define NPX  65536            // 16 * 4096 pixels
#define MARGIN 0.15f

typedef unsigned short u16;
typedef __attribute__((ext_vector_type(8)))  _Float16 half8;
typedef __attribute__((ext_vector_type(8)))  unsigned short ushort8;
typedef __attribute__((ext_vector_type(16))) float  f32x16;

__device__ __forceinline__ u16 f2h(float f) {
    return __builtin_bit_cast(u16, (_Float16)f);   // v_cvt_f16_f32, RN
}

// Pack cluster centers into fp16 MFMA A-operand fragment order, grouped by
// k-half, and compute 0.5*c_sq (exact fp32). Also zeroes the flag counter.
// wcc layout: [chunk 32][half 2][unit 8][lane 64][8 fp16];
// unit = local m-tile (32 clusters each).
__global__ __launch_bounds__(64) void prep_pack(const float* __restrict__ cc,
                                                u16* __restrict__ wcc,
                                                float* __restrict__ shalf,
                                                int* __restrict__ gcnt) {
    const int k    = blockIdx.x;
    const int lane = threadIdx.x;      // 64 j-groups of 8 channels
    if (k == 0 && lane == 0) gcnt[0] = 0;
    const int c0   = lane * 8;
    const float* row = cc + (size_t)k * NC + c0;
    ushort8 hi;
    float sum = 0.f;
    #pragma unroll
    for (int i = 0; i < 8; ++i) {
        float v = row[i];
        sum = fmaf(v, v, sum);
        hi[i] = f2h(v);
    }
    const int ch  = c0 >> 4;           // 16-channel chunk
    const int kh  = (c0 >> 3) & 1;     // which 8-chan octet of the chunk
    const int mtg = k >> 5;            // global m-tile 0..15
    const int h   = mtg >> 3;          // k-half
    const int mtl = mtg & 7;           // local m-tile 0..7
    const int ls  = (k & 31) + 32 * kh;
    *(ushort8*)(wcc + (((size_t)(ch * 2 + h) * 8 + mtl) * 64 + ls) * 8) = hi;
    #pragma unroll
    for (int off = 32; off > 0; off >>= 1) sum += __shfl_down(sum, off, 64);
    if (lane == 0) shalf[k] = 0.5f * sum;
}

__global__ __launch_bounds__(256, 4) void codebook_mfma(
        const float* __restrict__ x,
        const u16* __restrict__ wcc,
        const float* __restrict__ shalf,
        float* __restrict__ cbv,          // [2][NPX] best v per half
        float* __restrict__ csv,          // [2][NPX] second v per half
        int*   __restrict__ ckk)          // [2][NPX] best k (global) per half
{
    __shared__ __align__(16) u16 cs0[8 * 512];    // 8KB cluster frags, buf 0
    __shared__ __align__(16) u16 cs1[8 * 512];    // 8KB cluster frags, buf 1
    __shared__ __align__(16) u16 xs0[2 * 512];    // 2KB x frags, buf 0
    __shared__ __align__(16) u16 xs1[2 * 512];    // 2KB x frags, buf 1
    // total 20480B. c_sq lives in the epilogue overlay.

    const int tid  = threadIdx.x;
    const int w    = tid >> 6;
    const int lane = tid & 63;

    const int h   = blockIdx.x & 1;               // k-half
    const int gp0 = (blockIdx.x >> 1) * 64;       // pixel-group base
    const float* xb = x + (size_t)(gp0 >> 12) * (NC * NHW) + (gp0 & (NHW - 1));

    f32x16 acc[2][2] = {};

    // x staging assignment: pixel p, chunk-octet kh, j-quarter jq (4 channels)
    const int p   = tid & 63;
    const int xkh = w & 1;
    const int jq  = w >> 1;
    const int xoff = ((p >> 5) * 64 + ((p & 31) + 32 * xkh)) * 8 + jq * 4;
    const float* xp = xb + (size_t)(xkh * 8 + jq * 4) * NHW + p;

    float fxa[4], fxb[4];                        // 2-deep x prefetch registers

    auto xload = [&](float* fx, int ch) {
        const float* xc = xp + (size_t)ch * 16 * NHW;
        fx[0] = xc[0];
        fx[1] = xc[NHW];
        fx[2] = xc[2 * NHW];
        fx[3] = xc[3 * NHW];
    };
    auto xwrite = [&](const float* fx, u16* xs) {
        u16 h0 = f2h(fx[0]), h1 = f2h(fx[1]), h2 = f2h(fx[2]), h3 = f2h(fx[3]);
        uint2 hv = make_uint2((unsigned)h0 | ((unsigned)h1 << 16),
                              (unsigned)h2 | ((unsigned)h3 << 16));
        *(uint2*)&xs[xoff] = hv;
    };
    // 8 units x 1KB = 8KB per chunk; 2 gload_lds per wave.
    auto stage_cs = [&](int ch, u16* dst) {
        #pragma unroll
        for (int i = 0; i < 2; ++i) {
            const int u = w * 2 + i;
            const u16* g = wcc + (((size_t)(ch * 2 + h) * 8 + u) * 64 + lane) * 8;
            __builtin_amdgcn_global_load_lds(
                (const __attribute__((address_space(1))) void*)g,
                (__attribute__((address_space(3))) void*)(dst + u * 512),
                16, 0, 0);
        }
    };
    auto compute = [&](const u16* csb, const u16* xsb) {
        __builtin_amdgcn_s_setprio(1);
        half8 bh[2];
        #pragma unroll
        for (int nt = 0; nt < 2; ++nt)
            bh[nt] = *(const half8*)&xsb[((size_t)nt * 64 + lane) * 8];
        #pragma unroll
        for (int mtl2 = 0; mtl2 < 2; ++mtl2) {
            const int gm = w * 2 + mtl2;          // local m-tile 0..7
            half8 ah = *(const half8*)&csb[((size_t)gm * 64 + lane) * 8];
            #pragma unroll
            for (int nt = 0; nt < 2; ++nt)
                acc[mtl2][nt] = __builtin_amdgcn_mfma_f32_32x32x16_f16(ah, bh[nt], acc[mtl2][nt], 0, 0, 0);
        }
        __builtin_amdgcn_s_setprio(0);
    };

    // vmcnt accounting (issue order pinned by sched_barrier(0)):
    // steady entry: fx_cur 4 outstanding. +2 stage -> 6; +4 xload -> 10.
    // vmcnt(6): fx_cur drained. vmcnt(4): stage drained, fx_nxt stays in
    // flight ACROSS the barrier.
    auto phase = [&](int t, u16* cs_cur, u16* cs_nxt, u16* xs_cur, u16* xs_nxt,
                     float* fx_cur, float* fx_nxt) {
        stage_cs(t + 1, cs_nxt);
        __builtin_amdgcn_sched_barrier(0);
        xload(fx_nxt, t + 2);
        asm volatile("s_waitcnt vmcnt(6)" ::: "memory");
        xwrite(fx_cur, xs_nxt);
        compute(cs_cur, xs_cur);
        asm volatile("s_waitcnt vmcnt(4) lgkmcnt(0)" ::: "memory");
        __builtin_amdgcn_s_barrier();
        __builtin_amdgcn_sched_barrier(0);
    };

    // ---- prologue ----
    xload(fxa, 0);                                    // 4 (oldest)
    __builtin_amdgcn_sched_barrier(0);
    stage_cs(0, cs0);                                 // +2 -> 6
    __builtin_amdgcn_sched_barrier(0);
    xload(fxb, 1);                                    // +4 -> 10
    asm volatile("s_waitcnt vmcnt(6)" ::: "memory");  // fxa ready
    xwrite(fxa, xs0);
    asm volatile("s_waitcnt vmcnt(4) lgkmcnt(0)" ::: "memory"); // cs0 done
    __builtin_amdgcn_s_barrier();
    __builtin_amdgcn_sched_barrier(0);

    // ---- main loop: chunks 0..29 ----
    for (int t = 0; t < 30; t += 2) {
        phase(t,     cs0, cs1, xs0, xs1, fxb, fxa);
        phase(t + 1, cs1, cs0, xs1, xs0, fxa, fxb);
    }

    // ---- tail: chunk 30 computes, chunk 31 staged ----
    stage_cs(31, cs1);                                // fxb(4) + 2 -> 6
    asm volatile("s_waitcnt vmcnt(2)" ::: "memory");  // fxb ready
    xwrite(fxb, xs1);
    compute(cs0, xs0);
    asm volatile("s_waitcnt vmcnt(0) lgkmcnt(0)" ::: "memory");
    __builtin_amdgcn_s_barrier();
    __builtin_amdgcn_sched_barrier(0);
    compute(cs1, xs1);
    __syncthreads();

    // ---- epilogue: per-half top-2 -> ws (overlays cs0, 7KB <= 8KB) ----
    float* cand_v = (float*)cs0;             // 2KB
    float* cand_s = cand_v + 512;            // 2KB
    int*   cand_k = (int*)(cand_s + 512);    // 2KB
    float* sh_ep  = (float*)(cand_k + 512);  // 1KB: 0.5*c_sq for this half

    sh_ep[tid] = shalf[h * 256 + tid];
    __syncthreads();

    const int qb = lane >> 5;
    #pragma unroll
    for (int nt = 0; nt < 2; ++nt) {
        float best = -INFINITY, sec = -INFINITY;
        int bk = 0;
        #pragma unroll
        for (int mtl2 = 0; mtl2 < 2; ++mtl2) {
            const int kbase = w * 64 + mtl2 * 32 + 4 * qb;
            #pragma unroll
            for (int reg = 0; reg < 16; ++reg) {
                const int k = kbase + (reg & 3) + 8 * (reg >> 2);  // ascending
                const float v = acc[mtl2][nt][reg] - sh_ep[k];
                if (v > best) { sec = best; best = v; bk = k; }
                else if (v > sec) sec = v;
            }
        }
        const int pc   = nt * 32 + (lane & 31);
        const int slot = w * 2 + qb;
        cand_v[pc * 8 + slot] = best;
        cand_s[pc * 8 + slot] = sec;
        cand_k[pc * 8 + slot] = bk;
    }
    __syncthreads();

    if (tid < 64) {
        float best = -INFINITY, sec = -INFINITY;
        int bk = 1 << 30;
        #pragma unroll
        for (int s = 0; s < 8; ++s) {
            float v  = cand_v[tid * 8 + s];
            float v2 = cand_s[tid * 8 + s];
            int  kk  = cand_k[tid * 8 + s];
            if (v > best || (v == best && kk < bk)) {
                sec = fmaxf(sec, best);
                best = v; bk = kk;
            } else sec = fmaxf(sec, v);
            sec = fmaxf(sec, v2);
        }
        const int gpx = gp0 + tid;
        cbv[h * NPX + gpx] = best;
        csv[h * NPX + gpx] = sec;
        ckk[h * NPX + gpx] = h * 256 + bk;
    }
}

// Per-pixel merge of the two k-halves; writes out; compacts near-tie pixels
// into a global list for the recheck kernel.
__global__ __launch_bounds__(256) void merge(
        const float* __restrict__ cbv,
        const float* __restrict__ csv,
        const int*   __restrict__ ckk,
        int* __restrict__ out,
        int* __restrict__ glist,
        int* __restrict__ gcnt)
{
    const int px = blockIdx.x * 256 + threadIdx.x;

    const float b0 = cbv[px],        b1 = cbv[NPX + px];
    const float s0 = csv[px],        s1 = csv[NPX + px];
    const int   k0 = ckk[px],        k1 = ckk[NPX + px];

    float best, sec; int bk;
    if (b0 >= b1) { best = b0; bk = k0; sec = fmaxf(s0, b1); }
    else          { best = b1; bk = k1; sec = fmaxf(s1, b0); }

    out[px] = bk;
    if (best - sec < MARGIN) {
        int i = atomicAdd(gcnt, 1);
        glist[i] = px;
    }
}

// One BLOCK per flagged pixel (grid-stride over the compacted list):
// cooperative fp64 exact distance over all 512 clusters.
__global__ __launch_bounds__(256) void recheck(
        const float* __restrict__ x,
        const float* __restrict__ cc,
        const int*   __restrict__ glist,
        const int*   __restrict__ gcnt,
        int* __restrict__ out)
{
    __shared__ float  xcol[NC];
    __shared__ double dvv[256];
    __shared__ int    dii[256];

    const int tid = threadIdx.x;
    const int n   = gcnt[0];

    for (int idx = blockIdx.x; idx < n; idx += gridDim.x) {
        const int gpx = glist[idx];
        const float* xb = x + (size_t)(gpx >> 12) * (NC * NHW);
        const int hw = gpx & (NHW - 1);
        for (int c = tid; c < NC; c += 256)
            xcol[c] = xb[(size_t)c * NHW + hw];
        __syncthreads();
        double bd = 1e300;
        int bkk = 1 << 30;
        #pragma unroll
        for (int r = 0; r < 2; ++r) {
            const int k = tid + r * 256;
            const float4* crow = (const float4*)(cc + (size_t)k * NC);
            const float4* xc4  = (const float4*)xcol;
            double da = 0.0, db = 0.0;           // 2-way split: halve chain latency
            for (int c4 = 0; c4 < NC / 4; ++c4) {
                float4 cv = crow[c4], xv = xc4[c4];
                double d0 = (double)xv.x - (double)cv.x;
                double d1 = (double)xv.y - (double)cv.y;
                double d2 = (double)xv.z - (double)cv.z;
                double d3 = (double)xv.w - (double)cv.w;
                da = fma(d0, d0, da); db = fma(d1, d1, db);
                da = fma(d2, d2, da); db = fma(d3, d3, db);
            }
            double d = da + db;
            if (d < bd || (d == bd && k < bkk)) { bd = d; bkk = k; }
        }
        dvv[tid] = bd; dii[tid] = bkk;
        __syncthreads();
        for (int srd = 128; srd > 0; srd >>= 1) {
            if (tid < srd) {
                double ov = dvv[tid + srd]; int oi = dii[tid + srd];
                if (ov < dvv[tid] || (ov == dvv[tid] && oi < dii[tid])) {
                    dvv[tid] = ov; dii[tid] = oi;
                }
            }
            __syncthreads();
        }
        if (tid == 0) out[gpx] = dii[0];
        __syncthreads();
    }
}

extern "C" void kernel_launch(void* const* d_in, const int* in_sizes, int n_in,
                              void* d_out, int out_size, void* d_ws, size_t ws_size,
                              hipStream_t stream) {
    const float* x  = (const float*)d_in[0];   // (16, 512, 64, 64) f32
    const float* cc = (const float*)d_in[1];   // (1, 512, 512, 1, 1) f32 -> [k][c]
    int* out = (int*)d_out;                    // (16, 1, 64, 64) int32

    float* shalf = (float*)d_ws;                          // 512 floats (2KB)
    u16*   wcc   = (u16*)(shalf + NK);                    // 512KB frag-ordered fp16
    float* cbv   = (float*)(wcc + 32 * 2 * 8 * 64 * 8);   // 2*NPX floats
    float* csv   = cbv + 2 * NPX;                         // 2*NPX floats
    int*   ckk   = (int*)(csv + 2 * NPX);                 // 2*NPX ints
    int*   glist = ckk + 2 * NPX;                         // NPX ints
    int*   gcnt  = glist + NPX;                           // 1 int

    prep_pack<<<NK, 64, 0, stream>>>(cc, wcc, shalf, gcnt);
    codebook_mfma<<<(NPX / 64) * 2, 256, 0, stream>>>(x, wcc, shalf, cbv, csv, ckk);
    merge<<<NPX / 256, 256, 0, stream>>>(cbv, csv, ckk, out, glist, gcnt);
    recheck<<<512, 256, 0, stream>>>(x, cc, glist, gcnt, out);
}

// Round 8
// 259.999 us; speedup vs baseline: 6.7855x; 1.5139x over previous
//
#include <hip/hip_runtime.h>
#include <math.h>

// Codebook argmin via fp16 MFMA: B=16, K=512, C=512, H=W=64.
// R3: K-SPLIT (256 clusters/block) -> 3 waves/SIMD, 237->141us.
// R4: parallel merge + recheck kernels (combine serialized at 153us).
// R5: 4 blocks/CU, LDS=40960.  R6: single fp16 MFMA + margin/recheck net.
// R7: launch_bounds (256,4) fixed the R6 spill; recheck now the tail:
// 165us -- uncoalesced per-thread cc rows (64-line gathers) + MARGIN=0.15
// flagging ~5% of pixels.
// R8: recheck rebuilt: (1) cc transposed to cct[c][k] (LDS-transpose kernel)
// so lanes own k and loads coalesce; (2) fp64 via cross only (-2*cross+csqd,
// csqd exact fp64 from prep); (3) MARGIN 0.05 (7.8 sigma of fp16 gap error);
// (4) 2 pixels per block pass to halve cct L2 traffic.

#define NK   512
#define NC   512
#define NHW  4096
#define NPX  65536            // 16 * 4096 pixels
#define MARGIN 0.05f

typedef unsigned short u16;
typedef __attribute__((ext_vector_type(8)))  _Float16 half8;
typedef __attribute__((ext_vector_type(8)))  unsigned short ushort8;
typedef __attribute__((ext_vector_type(16))) float  f32x16;

__device__ __forceinline__ u16 f2h(float f) {
    return __builtin_bit_cast(u16, (_Float16)f);   // v_cvt_f16_f32, RN
}

// Pack cluster centers into fp16 MFMA A-operand fragment order, grouped by
// k-half; compute 0.5*c_sq (fp32) and exact fp64 c_sq. Zero flag counter.
// wcc layout: [chunk 32][half 2][unit 8][lane 64][8 fp16].
__global__ __launch_bounds__(64) void prep_pack(const float* __restrict__ cc,
                                                u16* __restrict__ wcc,
                                                float* __restrict__ shalf,
                                                double* __restrict__ csqd,
                                                int* __restrict__ gcnt) {
    const int k    = blockIdx.x;
    const int lane = threadIdx.x;      // 64 j-groups of 8 channels
    if (k == 0 && lane == 0) gcnt[0] = 0;
    const int c0   = lane * 8;
    const float* row = cc + (size_t)k * NC + c0;
    ushort8 hi;
    double dsum = 0.0;
    #pragma unroll
    for (int i = 0; i < 8; ++i) {
        float v = row[i];
        dsum = fma((double)v, (double)v, dsum);
        hi[i] = f2h(v);
    }
    const int ch  = c0 >> 4;           // 16-channel chunk
    const int kh  = (c0 >> 3) & 1;     // which 8-chan octet of the chunk
    const int mtg = k >> 5;            // global m-tile 0..15
    const int h   = mtg >> 3;          // k-half
    const int mtl = mtg & 7;           // local m-tile 0..7
    const int ls  = (k & 31) + 32 * kh;
    *(ushort8*)(wcc + (((size_t)(ch * 2 + h) * 8 + mtl) * 64 + ls) * 8) = hi;
    #pragma unroll
    for (int off = 32; off > 0; off >>= 1) dsum += __shfl_down(dsum, off, 64);
    if (lane == 0) {
        csqd[k]  = dsum;
        shalf[k] = 0.5f * (float)dsum;
    }
}

// 64x64-tile LDS transpose: cct[c][k] = cc[k][c]. Grid 64 blocks x 256 thr.
__global__ __launch_bounds__(256) void transpose_cc(const float* __restrict__ cc,
                                                    float* __restrict__ cct) {
    __shared__ float tile[64][65];
    const int bi = blockIdx.x >> 3;    // k-tile
    const int bj = blockIdx.x & 7;     // c-tile
    const int tx = threadIdx.x & 63;
    const int ty = threadIdx.x >> 6;
    #pragma unroll
    for (int i = 0; i < 16; ++i) {
        const int r = ty + 4 * i;
        tile[r][tx] = cc[(size_t)(bi * 64 + r) * NC + bj * 64 + tx];
    }
    __syncthreads();
    #pragma unroll
    for (int i = 0; i < 16; ++i) {
        const int r = ty + 4 * i;
        cct[(size_t)(bj * 64 + r) * NK + bi * 64 + tx] = tile[tx][r];
    }
}

__global__ __launch_bounds__(256, 4) void codebook_mfma(
        const float* __restrict__ x,
        const u16* __restrict__ wcc,
        const float* __restrict__ shalf,
        float* __restrict__ cbv,          // [2][NPX] best v per half
        float* __restrict__ csv,          // [2][NPX] second v per half
        int*   __restrict__ ckk)          // [2][NPX] best k (global) per half
{
    __shared__ __align__(16) u16 cs0[8 * 512];    // 8KB cluster frags, buf 0
    __shared__ __align__(16) u16 cs1[8 * 512];    // 8KB cluster frags, buf 1
    __shared__ __align__(16) u16 xs0[2 * 512];    // 2KB x frags, buf 0
    __shared__ __align__(16) u16 xs1[2 * 512];    // 2KB x frags, buf 1
    // total 20480B. c_sq lives in the epilogue overlay.

    const int tid  = threadIdx.x;
    const int w    = tid >> 6;
    const int lane = tid & 63;

    const int h   = blockIdx.x & 1;               // k-half
    const int gp0 = (blockIdx.x >> 1) * 64;       // pixel-group base
    const float* xb = x + (size_t)(gp0 >> 12) * (NC * NHW) + (gp0 & (NHW - 1));

    f32x16 acc[2][2] = {};

    // x staging assignment: pixel p, chunk-octet kh, j-quarter jq (4 channels)
    const int p   = tid & 63;
    const int xkh = w & 1;
    const int jq  = w >> 1;
    const int xoff = ((p >> 5) * 64 + ((p & 31) + 32 * xkh)) * 8 + jq * 4;
    const float* xp = xb + (size_t)(xkh * 8 + jq * 4) * NHW + p;

    float fxa[4], fxb[4];                        // 2-deep x prefetch registers

    auto xload = [&](float* fx, int ch) {
        const float* xc = xp + (size_t)ch * 16 * NHW;
        fx[0] = xc[0];
        fx[1] = xc[NHW];
        fx[2] = xc[2 * NHW];
        fx[3] = xc[3 * NHW];
    };
    auto xwrite = [&](const float* fx, u16* xs) {
        u16 h0 = f2h(fx[0]), h1 = f2h(fx[1]), h2 = f2h(fx[2]), h3 = f2h(fx[3]);
        uint2 hv = make_uint2((unsigned)h0 | ((unsigned)h1 << 16),
                              (unsigned)h2 | ((unsigned)h3 << 16));
        *(uint2*)&xs[xoff] = hv;
    };
    // 8 units x 1KB = 8KB per chunk; 2 gload_lds per wave.
    auto stage_cs = [&](int ch, u16* dst) {
        #pragma unroll
        for (int i = 0; i < 2; ++i) {
            const int u = w * 2 + i;
            const u16* g = wcc + (((size_t)(ch * 2 + h) * 8 + u) * 64 + lane) * 8;
            __builtin_amdgcn_global_load_lds(
                (const __attribute__((address_space(1))) void*)g,
                (__attribute__((address_space(3))) void*)(dst + u * 512),
                16, 0, 0);
        }
    };
    auto compute = [&](const u16* csb, const u16* xsb) {
        __builtin_amdgcn_s_setprio(1);
        half8 bh[2];
        #pragma unroll
        for (int nt = 0; nt < 2; ++nt)
            bh[nt] = *(const half8*)&xsb[((size_t)nt * 64 + lane) * 8];
        #pragma unroll
        for (int mtl2 = 0; mtl2 < 2; ++mtl2) {
            const int gm = w * 2 + mtl2;          // local m-tile 0..7
            half8 ah = *(const half8*)&csb[((size_t)gm * 64 + lane) * 8];
            #pragma unroll
            for (int nt = 0; nt < 2; ++nt)
                acc[mtl2][nt] = __builtin_amdgcn_mfma_f32_32x32x16_f16(ah, bh[nt], acc[mtl2][nt], 0, 0, 0);
        }
        __builtin_amdgcn_s_setprio(0);
    };

    // vmcnt accounting (issue order pinned by sched_barrier(0)):
    // steady entry: fx_cur 4 outstanding. +2 stage -> 6; +4 xload -> 10.
    // vmcnt(6): fx_cur drained. vmcnt(4): stage drained, fx_nxt stays in
    // flight ACROSS the barrier.
    auto phase = [&](int t, u16* cs_cur, u16* cs_nxt, u16* xs_cur, u16* xs_nxt,
                     float* fx_cur, float* fx_nxt) {
        stage_cs(t + 1, cs_nxt);
        __builtin_amdgcn_sched_barrier(0);
        xload(fx_nxt, t + 2);
        asm volatile("s_waitcnt vmcnt(6)" ::: "memory");
        xwrite(fx_cur, xs_nxt);
        compute(cs_cur, xs_cur);
        asm volatile("s_waitcnt vmcnt(4) lgkmcnt(0)" ::: "memory");
        __builtin_amdgcn_s_barrier();
        __builtin_amdgcn_sched_barrier(0);
    };

    // ---- prologue ----
    xload(fxa, 0);                                    // 4 (oldest)
    __builtin_amdgcn_sched_barrier(0);
    stage_cs(0, cs0);                                 // +2 -> 6
    __builtin_amdgcn_sched_barrier(0);
    xload(fxb, 1);                                    // +4 -> 10
    asm volatile("s_waitcnt vmcnt(6)" ::: "memory");  // fxa ready
    xwrite(fxa, xs0);
    asm volatile("s_waitcnt vmcnt(4) lgkmcnt(0)" ::: "memory"); // cs0 done
    __builtin_amdgcn_s_barrier();
    __builtin_amdgcn_sched_barrier(0);

    // ---- main loop: chunks 0..29 ----
    for (int t = 0; t < 30; t += 2) {
        phase(t,     cs0, cs1, xs0, xs1, fxb, fxa);
        phase(t + 1, cs1, cs0, xs1, xs0, fxa, fxb);
    }

    // ---- tail: chunk 30 computes, chunk 31 staged ----
    stage_cs(31, cs1);                                // fxb(4) + 2 -> 6
    asm volatile("s_waitcnt vmcnt(2)" ::: "memory");  // fxb ready
    xwrite(fxb, xs1);
    compute(cs0, xs0);
    asm volatile("s_waitcnt vmcnt(0) lgkmcnt(0)" ::: "memory");
    __builtin_amdgcn_s_barrier();
    __builtin_amdgcn_sched_barrier(0);
    compute(cs1, xs1);
    __syncthreads();

    // ---- epilogue: per-half top-2 -> ws (overlays cs0, 7KB <= 8KB) ----
    float* cand_v = (float*)cs0;             // 2KB
    float* cand_s = cand_v + 512;            // 2KB
    int*   cand_k = (int*)(cand_s + 512);    // 2KB
    float* sh_ep  = (float*)(cand_k + 512);  // 1KB: 0.5*c_sq for this half

    sh_ep[tid] = shalf[h * 256 + tid];
    __syncthreads();

    const int qb = lane >> 5;
    #pragma unroll
    for (int nt = 0; nt < 2; ++nt) {
        float best = -INFINITY, sec = -INFINITY;
        int bk = 0;
        #pragma unroll
        for (int mtl2 = 0; mtl2 < 2; ++mtl2) {
            const int kbase = w * 64 + mtl2 * 32 + 4 * qb;
            #pragma unroll
            for (int reg = 0; reg < 16; ++reg) {
                const int k = kbase + (reg & 3) + 8 * (reg >> 2);  // ascending
                const float v = acc[mtl2][nt][reg] - sh_ep[k];
                if (v > best) { sec = best; best = v; bk = k; }
                else if (v > sec) sec = v;
            }
        }
        const int pc   = nt * 32 + (lane & 31);
        const int slot = w * 2 + qb;
        cand_v[pc * 8 + slot] = best;
        cand_s[pc * 8 + slot] = sec;
        cand_k[pc * 8 + slot] = bk;
    }
    __syncthreads();

    if (tid < 64) {
        float best = -INFINITY, sec = -INFINITY;
        int bk = 1 << 30;
        #pragma unroll
        for (int s = 0; s < 8; ++s) {
            float v  = cand_v[tid * 8 + s];
            float v2 = cand_s[tid * 8 + s];
            int  kk  = cand_k[tid * 8 + s];
            if (v > best || (v == best && kk < bk)) {
                sec = fmaxf(sec, best);
                best = v; bk = kk;
            } else sec = fmaxf(sec, v);
            sec = fmaxf(sec, v2);
        }
        const int gpx = gp0 + tid;
        cbv[h * NPX + gpx] = best;
        csv[h * NPX + gpx] = sec;
        ckk[h * NPX + gpx] = h * 256 + bk;
    }
}

// Per-pixel merge of the two k-halves; writes out; compacts near-tie pixels
// into a global list for the recheck kernel.
__global__ __launch_bounds__(256) void merge(
        const float* __restrict__ cbv,
        const float* __restrict__ csv,
        const int*   __restrict__ ckk,
        int* __restrict__ out,
        int* __restrict__ glist,
        int* __restrict__ gcnt)
{
    const int px = blockIdx.x * 256 + threadIdx.x;

    const float b0 = cbv[px],        b1 = cbv[NPX + px];
    const float s0 = csv[px],        s1 = csv[NPX + px];
    const int   k0 = ckk[px],        k1 = ckk[NPX + px];

    float best, sec; int bk;
    if (b0 >= b1) { best = b0; bk = k0; sec = fmaxf(s0, b1); }
    else          { best = b1; bk = k1; sec = fmaxf(s1, b0); }

    out[px] = bk;
    if (best - sec < MARGIN) {
        int i = atomicAdd(gcnt, 1);
        glist[i] = px;
    }
}

// Exact fp64 recheck, 2 pixels per block pass. Lane l owns clusters
// k = l*8..l*8+7 (coalesced float4 pairs from cct); wave w covers c-quarter
// [w*128, w*128+128). dist ordering = -2*cross + csqd (x_sq common).
__global__ __launch_bounds__(256) void recheck(
        const float* __restrict__ x,
        const float* __restrict__ cct,     // [c][k] transposed centers
        const double* __restrict__ csqd,   // exact fp64 c_sq
        const int*   __restrict__ glist,
        const int*   __restrict__ gcnt,
        int* __restrict__ out)
{
    __shared__ float  xcol[2][NC];            // 4KB
    __shared__ double part[2][4][NK];         // 32KB
    __shared__ double dvv[256];               // 2KB
    __shared__ int    dii[256];               // 1KB

    const int tid  = threadIdx.x;
    const int w    = tid >> 6;
    const int lane = tid & 63;
    const int n    = gcnt[0];
    const int nb   = (n + 1) >> 1;

    for (int idx = blockIdx.x; idx < nb; idx += gridDim.x) {
        const int i0 = idx * 2;
        const int i1 = i0 + 1;
        const int px0 = glist[i0];
        const int px1 = (i1 < n) ? glist[i1] : px0;

        // stage both x columns
        #pragma unroll
        for (int r = 0; r < 2; ++r) {
            const int c = tid + r * 256;
            xcol[0][c] = x[(size_t)(px0 >> 12) * (NC * NHW) + (size_t)c * NHW + (px0 & (NHW - 1))];
            xcol[1][c] = x[(size_t)(px1 >> 12) * (NC * NHW) + (size_t)c * NHW + (px1 & (NHW - 1))];
        }
        __syncthreads();

        // fp64 cross accumulation over this wave's c-quarter
        double a0[8] = {}, a1[8] = {};
        const float4* cr = (const float4*)(cct + (size_t)(w * 128) * NK) + lane * 2;
        #pragma unroll 4
        for (int c0 = 0; c0 < 128; ++c0) {
            const float4 va = cr[0];
            const float4 vb = cr[1];
            cr += NK / 4;
            const double x0 = (double)xcol[0][w * 128 + c0];
            const double x1 = (double)xcol[1][w * 128 + c0];
            const double c4[8] = {(double)va.x, (double)va.y, (double)va.z, (double)va.w,
                                  (double)vb.x, (double)vb.y, (double)vb.z, (double)vb.w};
            #pragma unroll
            for (int j = 0; j < 8; ++j) {
                a0[j] = fma(x0, c4[j], a0[j]);
                a1[j] = fma(x1, c4[j], a1[j]);
            }
        }
        #pragma unroll
        for (int j = 0; j < 8; ++j) {
            part[0][w][lane * 8 + j] = a0[j];
            part[1][w][lane * 8 + j] = a1[j];
        }
        __syncthreads();

        // per-pixel argmin over 512 clusters (2 k per thread), then tree
        #pragma unroll
        for (int pxi = 0; pxi < 2; ++pxi) {
            double bd = 1e300;
            int bkk = 1 << 30;
            #pragma unroll
            for (int r = 0; r < 2; ++r) {
                const int k = tid + r * 256;
                const double cross = part[pxi][0][k] + part[pxi][1][k]
                                   + part[pxi][2][k] + part[pxi][3][k];
                const double d = fma(-2.0, cross, csqd[k]);
                if (d < bd || (d == bd && k < bkk)) { bd = d; bkk = k; }
            }
            dvv[tid] = bd; dii[tid] = bkk;
            __syncthreads();
            for (int srd = 128; srd > 0; srd >>= 1) {
                if (tid < srd) {
                    double ov = dvv[tid + srd]; int oi = dii[tid + srd];
                    if (ov < dvv[tid] || (ov == dvv[tid] && oi < dii[tid])) {
                        dvv[tid] = ov; dii[tid] = oi;
                    }
                }
                __syncthreads();
            }
            if (tid == 0) out[pxi == 0 ? px0 : px1] = dii[0];
            __syncthreads();
        }
    }
}

extern "C" void kernel_launch(void* const* d_in, const int* in_sizes, int n_in,
                              void* d_out, int out_size, void* d_ws, size_t ws_size,
                              hipStream_t stream) {
    const float* x  = (const float*)d_in[0];   // (16, 512, 64, 64) f32
    const float* cc = (const float*)d_in[1];   // (1, 512, 512, 1, 1) f32 -> [k][c]
    int* out = (int*)d_out;                    // (16, 1, 64, 64) int32

    double* csqd  = (double*)d_ws;                        // 512 doubles (4KB)
    float*  shalf = (float*)(csqd + NK);                  // 512 floats (2KB)
    u16*    wcc   = (u16*)(shalf + NK);                   // 512KB frag-ordered fp16
    float*  cct   = (float*)(wcc + 32 * 2 * 8 * 64 * 8);  // 1MB transposed centers
    float*  cbv   = cct + (size_t)NC * NK;                // 2*NPX floats
    float*  csv   = cbv + 2 * NPX;                        // 2*NPX floats
    int*    ckk   = (int*)(csv + 2 * NPX);                // 2*NPX ints
    int*    glist = ckk + 2 * NPX;                        // NPX ints
    int*    gcnt  = glist + NPX;                          // 1 int

    prep_pack<<<NK, 64, 0, stream>>>(cc, wcc, shalf, csqd, gcnt);
    transpose_cc<<<64, 256, 0, stream>>>(cc, cct);
    codebook_mfma<<<(NPX / 64) * 2, 256, 0, stream>>>(x, wcc, shalf, cbv, csv, ckk);
    merge<<<NPX / 256, 256, 0, stream>>>(cbv, csv, ckk, out, glist, gcnt);
    recheck<<<1024, 256, 0, stream>>>(x, cct, csqd, glist, gcnt, out);
}